// Round 4
// baseline (275.017 us; speedup 1.0000x reference)
//
#include <hip/hip_runtime.h>
#include <hip/hip_bf16.h>
#include <stdint.h>

#define KTOT 8192
#define BM 64
#define BK 128
#define KSPLIT 4
#define KCHUNK (KTOT / KSPLIT)   // 2048
#define NIT (KCHUNK / BK)        // 16

typedef __attribute__((ext_vector_type(8))) __bf16 bf16x8;
typedef __attribute__((ext_vector_type(4))) float f32x4;

__device__ __forceinline__ unsigned short f2bf(float f) {
  union { float f; unsigned int u; } a;
  a.f = f;
  unsigned int r = (a.u + 0x7fffu + ((a.u >> 16) & 1u)) >> 16;
  return (unsigned short)r;
}

__device__ __forceinline__ uint2 pack4(f32x4 v) {
  union { unsigned short h[4]; uint2 u; } pk;
  pk.h[0] = f2bf(v[0]); pk.h[1] = f2bf(v[1]);
  pk.h[2] = f2bf(v[2]); pk.h[3] = f2bf(v[3]);
  return pk.u;
}

// x [8192][64] f32  ->  xt [64][8192] bf16 (transposed)
__global__ __launch_bounds__(256) void xpose_f32_bf16(const float* __restrict__ x,
                                                      __hip_bfloat16* __restrict__ xt) {
  __shared__ unsigned short tile[64][72];
  const int r0 = blockIdx.x * 64;
  const int t = threadIdx.x;
  const int a = t >> 4;
  const int c4 = (t & 15) * 4;
#pragma unroll
  for (int rep = 0; rep < 4; ++rep) {
    int r = a + rep * 16;
    float4 v = *reinterpret_cast<const float4*>(x + (size_t)(r0 + r) * 64 + c4);
    tile[c4 + 0][r] = f2bf(v.x);
    tile[c4 + 1][r] = f2bf(v.y);
    tile[c4 + 2][r] = f2bf(v.z);
    tile[c4 + 3][r] = f2bf(v.w);
  }
  __syncthreads();
#pragma unroll
  for (int rep = 0; rep < 4; ++rep) {
    int j = a + rep * 16;
    uint2 v = *reinterpret_cast<const uint2*>(&tile[j][c4]);
    *reinterpret_cast<uint2*>((unsigned short*)xt + (size_t)j * KTOT + r0 + c4) = v;
  }
}

// part[kc][col][row] (f32, [KSPLIT][128][8192]) = raw C partials of
// C = A(f32 [8192][8192]) @ B, B transposed bf16 BT[128][8192].
// BM=64, 8 waves: wave w owns cols w*16..+15, all 4 M-tiles (B frag reused 4x).
// grid 512: mblk = bid&127, kc = bid>>7. Depth-2 reg prefetch, 2 blocks/CU.
__global__ __launch_bounds__(512, 4) void gemm_part(
    const float* __restrict__ A, const __hip_bfloat16* __restrict__ BTv,
    float* __restrict__ part) {
  constexpr int SZ_A = BM * BK * 2;   // 16 KiB bf16
  __shared__ __align__(16) unsigned char smem[2 * SZ_A];
  const unsigned short* BT = (const unsigned short*)BTv;

  const int bid = blockIdx.x;
  const int kc = bid >> 7;
  const int mblk = bid & 127;
  const int r0 = mblk * BM;
  const int kbase = kc * KCHUNK;

  const int t = threadIdx.x;
  const int l = t & 63;
  const int w = t >> 6;

  // ---- A staging: 64x128 f32 tile, 4 float4 per thread ----
  const float* aptr[4];
  int loff_a[4];
#pragma unroll
  for (int r = 0; r < 4; ++r) {
    int idx = t + r * 512;
    int m = idx >> 5, c4 = idx & 31;
    aptr[r] = A + (size_t)(r0 + m) * KTOT + kbase + c4 * 4;
    loff_a[r] = m * 256 + ((c4 * 8) ^ ((m & 7) << 4));
  }

  const int lr = l & 15;
  const int g = l >> 4;
  const int col = w * 16 + lr;
  const unsigned short* bptr = BT + (size_t)col * KTOT + kbase + g * 8;
  const int asw = (lr & 7) << 4;

  f32x4 acc[4];
  const f32x4 fzero = {0.f, 0.f, 0.f, 0.f};
#pragma unroll
  for (int mt = 0; mt < 4; ++mt) acc[mt] = fzero;

  float4 av0[4], av1[4];
  bf16x8 Bf0[4], Bf1[4];
  unsigned char* lds0 = smem;
  unsigned char* lds1 = smem + SZ_A;

#define LOAD_A(AV, K0)                                                        \
  _Pragma("unroll") for (int r = 0; r < 4; ++r)                               \
      AV[r] = *reinterpret_cast<const float4*>(aptr[r] + (K0));
#define LOAD_B(BF, K0)                                                        \
  _Pragma("unroll") for (int ks = 0; ks < 4; ++ks)                            \
      BF[ks] = *reinterpret_cast<const bf16x8*>(bptr + (K0) + ks * 32);
#define WRITE_A(LDS, AV)                                                      \
  _Pragma("unroll") for (int r = 0; r < 4; ++r) {                             \
    f32x4 v_ = {AV[r].x, AV[r].y, AV[r].z, AV[r].w};                          \
    *reinterpret_cast<uint2*>((LDS) + loff_a[r]) = pack4(v_);                 \
  }
#define COMPUTE(LDS, BF)                                                      \
  _Pragma("unroll") for (int ks = 0; ks < 4; ++ks) {                          \
    _Pragma("unroll") for (int mt = 0; mt < 4; ++mt) {                        \
      bf16x8 af_ = *reinterpret_cast<const bf16x8*>(                          \
          (LDS) + (mt * 16 + lr) * 256 + ((ks * 64 + g * 16) ^ asw));         \
      acc[mt] = __builtin_amdgcn_mfma_f32_16x16x32_bf16(af_, BF[ks], acc[mt], \
                                                        0, 0, 0);             \
    }                                                                         \
  }

  // prologue: tiles 0,1 in flight; tile 0 -> lds0
  LOAD_A(av0, 0); LOAD_B(Bf0, 0);
  LOAD_A(av1, BK); LOAD_B(Bf1, BK);
  WRITE_A(lds0, av0);
  __syncthreads();

#pragma unroll 1
  for (int it = 0; it < NIT; it += 2) {
    // phase even: tile it (set 0, lds0); prefetch it+2 into set 0
    if (it + 2 < NIT) { LOAD_A(av0, (it + 2) * BK); }
    COMPUTE(lds0, Bf0);
    if (it + 2 < NIT) { LOAD_B(Bf0, (it + 2) * BK); }
    if (it + 1 < NIT) { WRITE_A(lds1, av1); }
    __syncthreads();
    // phase odd: tile it+1 (set 1, lds1); prefetch it+3 into set 1
    if (it + 3 < NIT) { LOAD_A(av1, (it + 3) * BK); }
    if (it + 1 < NIT) { COMPUTE(lds1, Bf1); }
    if (it + 3 < NIT) { LOAD_B(Bf1, (it + 3) * BK); }
    if (it + 2 < NIT) { WRITE_A(lds0, av0); }
    __syncthreads();
  }

  // raw partial store: part[kc*128+col][r0 + mt*16 + g*4 .. +3]
  float* pp = part + (size_t)(kc * 128 + col) * KTOT + r0 + g * 4;
#pragma unroll
  for (int mt = 0; mt < 4; ++mt)
    *reinterpret_cast<f32x4*>(pp + mt * 16) = acc[mt];
#undef LOAD_A
#undef LOAD_B
#undef WRITE_A
#undef COMPUTE
}

// Combine KSPLIT partials + epilogue, separate halves (lo: cols 0-63, hi: 64-127).
// Optional bt store (bf16 transposed raw C), optional out write (scaled,
// optional add for lo half, optional accumulate). 256 blocks x 32 rows.
__global__ __launch_bounds__(256) void reduce_sep(
    const float* __restrict__ part, float* __restrict__ out,
    const float* s_lo_p, const float* s_hi_p,
    const float* __restrict__ add_ptr, const float* add_s_p,
    __hip_bfloat16* bt_lo, __hip_bfloat16* bt_hi,
    int base_lo, int base_hi, int accum) {
  const int t = threadIdx.x;
  const int col = t & 127;
  const int rbase = blockIdx.x * 32 + (t >> 7) * 16;
  const float* p0 = part + (size_t)col * KTOT + rbase;
  const bool hi = col >= 64;
  const int col64 = hi ? col - 64 : col;
  __hip_bfloat16* bt = hi ? bt_hi : bt_lo;
  const int obase = hi ? base_hi : base_lo;
  const float s = hi ? (s_hi_p ? *s_hi_p : 0.f) : (s_lo_p ? *s_lo_p : 0.f);
  const float was = add_s_p ? *add_s_p : 0.f;
#pragma unroll
  for (int i = 0; i < 4; ++i) {
    f32x4 c = *reinterpret_cast<const f32x4*>(p0 + 4 * i);
#pragma unroll
    for (int k = 1; k < KSPLIT; ++k)
      c += *reinterpret_cast<const f32x4*>(p0 + (size_t)k * 128 * KTOT + 4 * i);
    if (bt)
      *reinterpret_cast<uint2*>((unsigned short*)bt + (size_t)col64 * KTOT + rbase + 4 * i) =
          pack4(c);
    if (obase >= 0) {
#pragma unroll
      for (int j = 0; j < 4; ++j) {
        int row = rbase + 4 * i + j;
        float v = s * c[j];
        if (add_ptr && !hi) v = fmaf(was, add_ptr[(size_t)row * 64 + col64], v);
        if (accum) v += out[(size_t)row * 128 + obase + col64];
        out[(size_t)row * 128 + obase + col64] = v;
      }
    }
  }
}

// Combine partials + cross-half epilogue: out[:,64+c] = s_lo*lo[c] + s_hi*hi[c],
// bt_lo = raw lo (bf16 transposed). 256 blocks x 32 rows.
__global__ __launch_bounds__(256) void reduce_comb(
    const float* __restrict__ part, float* __restrict__ out,
    const float* s_lo_p, const float* s_hi_p, __hip_bfloat16* bt_lo) {
  const int t = threadIdx.x;
  const int c = t & 63;
  const int rbase = blockIdx.x * 32 + (t >> 6) * 8;
  const float* pl = part + (size_t)c * KTOT + rbase;
  const float* ph = part + (size_t)(c + 64) * KTOT + rbase;
  const float sl = *s_lo_p, sh = *s_hi_p;
#pragma unroll
  for (int i = 0; i < 2; ++i) {
    f32x4 lo = *reinterpret_cast<const f32x4*>(pl + 4 * i);
    f32x4 hv = *reinterpret_cast<const f32x4*>(ph + 4 * i);
#pragma unroll
    for (int k = 1; k < KSPLIT; ++k) {
      lo += *reinterpret_cast<const f32x4*>(pl + (size_t)k * 128 * KTOT + 4 * i);
      hv += *reinterpret_cast<const f32x4*>(ph + (size_t)k * 128 * KTOT + 4 * i);
    }
    *reinterpret_cast<uint2*>((unsigned short*)bt_lo + (size_t)c * KTOT + rbase + 4 * i) =
        pack4(lo);
#pragma unroll
    for (int j = 0; j < 4; ++j) {
      int row = rbase + 4 * i + j;
      out[(size_t)row * 128 + 64 + c] = sl * lo[j] + sh * hv[j];
    }
  }
}

extern "C" void kernel_launch(void* const* d_in, const int* in_sizes, int n_in,
                              void* d_out, int out_size, void* d_ws, size_t ws_size,
                              hipStream_t stream) {
  const float* A_p = (const float*)d_in[0];
  const float* A_n = (const float*)d_in[1];
  const float* x_p = (const float*)d_in[2];
  const float* x_n = (const float*)d_in[3];
  const float* w_p = (const float*)d_in[4];  // [3]
  const float* w_n = (const float*)d_in[5];  // [3]
  float* out = (float*)d_out;                // [8192][128]

  // ws layout (21 MiB):
  //   BTbig [192][8192] bf16: rows 0-63 x_p^T, 64-127 x_n^T, 128-191 Y1^T
  //   B3T   [128][8192] bf16: rows 0-63 P1^T, 64-127 T1^T
  //   part  [KSPLIT][128][8192] f32
  __hip_bfloat16* BTbig = (__hip_bfloat16*)d_ws;
  __hip_bfloat16* B3T = BTbig + (size_t)192 * KTOT;
  float* part = (float*)(B3T + (size_t)128 * KTOT);

  xpose_f32_bf16<<<128, 256, 0, stream>>>(x_p, BTbig);
  xpose_f32_bf16<<<128, 256, 0, stream>>>(x_n, BTbig + (size_t)64 * KTOT);

  // G1: [P1|Y1] = A_p @ [x_p|x_n]
  gemm_part<<<512, 512, 0, stream>>>(A_p, BTbig, part);
  // out[:,0:64] = wp0*x_p + wp1*P1; emit P1^T -> B3T[0:64], Y1^T -> BTbig[128:192]
  reduce_sep<<<256, 256, 0, stream>>>(part, out, w_p + 1, nullptr, x_p, w_p + 0,
                                      B3T, BTbig + (size_t)128 * KTOT, 0, -1, 0);

  // G2': [T1|T3] = A_n @ [x_n|Y1]
  gemm_part<<<512, 512, 0, stream>>>(A_n, BTbig + (size_t)64 * KTOT, part);
  // out[:,64:128] = wn0*T1 + wn2*T3; emit T1^T -> B3T[64:128]
  reduce_comb<<<256, 256, 0, stream>>>(part, out, w_n + 0, w_n + 2,
                                       B3T + (size_t)64 * KTOT);

  // G3: [P2|T2] = A_p @ [P1|T1]
  gemm_part<<<512, 512, 0, stream>>>(A_p, B3T, part);
  // out[:,0:64] += wp2*P2; out[:,64:128] += wn1*T2
  reduce_sep<<<256, 256, 0, stream>>>(part, out, w_p + 2, w_n + 1, nullptr, nullptr,
                                      nullptr, nullptr, 0, 64, 1);
}

// Round 5
// 258.368 us; speedup vs baseline: 1.0644x; 1.0644x over previous
//
#include <hip/hip_runtime.h>
#include <hip/hip_bf16.h>
#include <stdint.h>

#define KTOT 8192
#define BM 64
#define BK 128
#define KSPLIT 4
#define KCHUNK (KTOT / KSPLIT)   // 2048
#define NIT (KCHUNK / BK)        // 16

typedef __attribute__((ext_vector_type(8))) __bf16 bf16x8;
typedef __attribute__((ext_vector_type(4))) float f32x4;

__device__ __forceinline__ unsigned short f2bf(float f) {
  union { float f; unsigned int u; } a;
  a.f = f;
  unsigned int r = (a.u + 0x7fffu + ((a.u >> 16) & 1u)) >> 16;
  return (unsigned short)r;
}

__device__ __forceinline__ uint2 pack4(f32x4 v) {
  union { unsigned short h[4]; uint2 u; } pk;
  pk.h[0] = f2bf(v[0]); pk.h[1] = f2bf(v[1]);
  pk.h[2] = f2bf(v[2]); pk.h[3] = f2bf(v[3]);
  return pk.u;
}

// x [8192][64] f32  ->  xt [64][8192] bf16 (transposed)
__global__ __launch_bounds__(256) void xpose_f32_bf16(const float* __restrict__ x,
                                                      __hip_bfloat16* __restrict__ xt) {
  __shared__ unsigned short tile[64][72];
  const int r0 = blockIdx.x * 64;
  const int t = threadIdx.x;
  const int a = t >> 4;
  const int c4 = (t & 15) * 4;
#pragma unroll
  for (int rep = 0; rep < 4; ++rep) {
    int r = a + rep * 16;
    f32x4 v = __builtin_nontemporal_load(
        reinterpret_cast<const f32x4*>(x + (size_t)(r0 + r) * 64 + c4));
    tile[c4 + 0][r] = f2bf(v[0]);
    tile[c4 + 1][r] = f2bf(v[1]);
    tile[c4 + 2][r] = f2bf(v[2]);
    tile[c4 + 3][r] = f2bf(v[3]);
  }
  __syncthreads();
#pragma unroll
  for (int rep = 0; rep < 4; ++rep) {
    int j = a + rep * 16;
    uint2 v = *reinterpret_cast<const uint2*>(&tile[j][c4]);
    *reinterpret_cast<uint2*>((unsigned short*)xt + (size_t)j * KTOT + r0 + c4) = v;
  }
}

// part[kc][col][row] (f32, [KSPLIT][128][8192]) = raw C partials of
// C = A(f32 [8192][8192]) @ B, B transposed bf16 BT[128][8192].
// BM=64, 8 waves: wave w owns cols w*16..+15, all 4 M-tiles (B frag reused 4x).
// grid 512. kc is XCD-affine (bid&7 -> same K-chunk) so each XCD's L2 holds
// only a 512 KB B slice. A loads + partial stores are non-temporal.
__global__ __launch_bounds__(512, 4) void gemm_part(
    const float* __restrict__ A, const __hip_bfloat16* __restrict__ BTv,
    float* __restrict__ part) {
  constexpr int SZ_A = BM * BK * 2;   // 16 KiB bf16
  __shared__ __align__(16) unsigned char smem[2 * SZ_A];
  const unsigned short* BT = (const unsigned short*)BTv;

  const int bid = blockIdx.x;
  const int kc = (bid & 7) >> 1;                 // XCD-affine K-chunk
  const int mblk = ((bid >> 3) << 1) | (bid & 1);
  const int r0 = mblk * BM;
  const int kbase = kc * KCHUNK;

  const int t = threadIdx.x;
  const int l = t & 63;
  const int w = t >> 6;

  // ---- A staging: 64x128 f32 tile, 4 float4 per thread ----
  const float* aptr[4];
  int loff_a[4];
#pragma unroll
  for (int r = 0; r < 4; ++r) {
    int idx = t + r * 512;
    int m = idx >> 5, c4 = idx & 31;
    aptr[r] = A + (size_t)(r0 + m) * KTOT + kbase + c4 * 4;
    loff_a[r] = m * 256 + ((c4 * 8) ^ ((m & 7) << 4));
  }

  const int lr = l & 15;
  const int g = l >> 4;
  const int col = w * 16 + lr;
  const unsigned short* bptr = BT + (size_t)col * KTOT + kbase + g * 8;
  const int asw = (lr & 7) << 4;

  f32x4 acc[4];
  const f32x4 fzero = {0.f, 0.f, 0.f, 0.f};
#pragma unroll
  for (int mt = 0; mt < 4; ++mt) acc[mt] = fzero;

  f32x4 av0[4], av1[4];
  bf16x8 Bf0[4], Bf1[4];
  unsigned char* lds0 = smem;
  unsigned char* lds1 = smem + SZ_A;

#define LOAD_A(AV, K0)                                                        \
  _Pragma("unroll") for (int r = 0; r < 4; ++r)                               \
      AV[r] = __builtin_nontemporal_load(                                     \
          reinterpret_cast<const f32x4*>(aptr[r] + (K0)));
#define LOAD_B(BF, K0)                                                        \
  _Pragma("unroll") for (int ks = 0; ks < 4; ++ks)                            \
      BF[ks] = *reinterpret_cast<const bf16x8*>(bptr + (K0) + ks * 32);
#define WRITE_A(LDS, AV)                                                      \
  _Pragma("unroll") for (int r = 0; r < 4; ++r) {                             \
    *reinterpret_cast<uint2*>((LDS) + loff_a[r]) = pack4(AV[r]);              \
  }
#define COMPUTE(LDS, BF)                                                      \
  _Pragma("unroll") for (int ks = 0; ks < 4; ++ks) {                          \
    _Pragma("unroll") for (int mt = 0; mt < 4; ++mt) {                        \
      bf16x8 af_ = *reinterpret_cast<const bf16x8*>(                          \
          (LDS) + (mt * 16 + lr) * 256 + ((ks * 64 + g * 16) ^ asw));         \
      acc[mt] = __builtin_amdgcn_mfma_f32_16x16x32_bf16(af_, BF[ks], acc[mt], \
                                                        0, 0, 0);             \
    }                                                                         \
  }

  // prologue: tiles 0,1 in flight; tile 0 -> lds0
  LOAD_A(av0, 0); LOAD_B(Bf0, 0);
  LOAD_A(av1, BK); LOAD_B(Bf1, BK);
  WRITE_A(lds0, av0);
  __syncthreads();

#pragma unroll 1
  for (int it = 0; it < NIT; it += 2) {
    // phase even: tile it (set 0, lds0); prefetch it+2 into set 0
    if (it + 2 < NIT) { LOAD_A(av0, (it + 2) * BK); }
    COMPUTE(lds0, Bf0);
    if (it + 2 < NIT) { LOAD_B(Bf0, (it + 2) * BK); }
    if (it + 1 < NIT) { WRITE_A(lds1, av1); }
    __syncthreads();
    // phase odd: tile it+1 (set 1, lds1); prefetch it+3 into set 1
    if (it + 3 < NIT) { LOAD_A(av1, (it + 3) * BK); }
    if (it + 1 < NIT) { COMPUTE(lds1, Bf1); }
    if (it + 3 < NIT) { LOAD_B(Bf1, (it + 3) * BK); }
    if (it + 2 < NIT) { WRITE_A(lds0, av0); }
    __syncthreads();
  }

  // raw partial store (non-temporal): part[kc*128+col][r0 + mt*16 + g*4 .. +3]
  float* pp = part + (size_t)(kc * 128 + col) * KTOT + r0 + g * 4;
#pragma unroll
  for (int mt = 0; mt < 4; ++mt)
    __builtin_nontemporal_store(acc[mt], reinterpret_cast<f32x4*>(pp + mt * 16));
#undef LOAD_A
#undef LOAD_B
#undef WRITE_A
#undef COMPUTE
}

// Combine KSPLIT partials + epilogue, separate halves (lo: cols 0-63, hi: 64-127).
// Optional bt store (bf16 transposed raw C), optional out write (scaled,
// optional add for lo half, optional accumulate). 256 blocks x 32 rows.
__global__ __launch_bounds__(256) void reduce_sep(
    const float* __restrict__ part, float* __restrict__ out,
    const float* s_lo_p, const float* s_hi_p,
    const float* __restrict__ add_ptr, const float* add_s_p,
    __hip_bfloat16* bt_lo, __hip_bfloat16* bt_hi,
    int base_lo, int base_hi, int accum) {
  const int t = threadIdx.x;
  const int col = t & 127;
  const int rbase = blockIdx.x * 32 + (t >> 7) * 16;
  const float* p0 = part + (size_t)col * KTOT + rbase;
  const bool hi = col >= 64;
  const int col64 = hi ? col - 64 : col;
  __hip_bfloat16* bt = hi ? bt_hi : bt_lo;
  const int obase = hi ? base_hi : base_lo;
  const float s = hi ? (s_hi_p ? *s_hi_p : 0.f) : (s_lo_p ? *s_lo_p : 0.f);
  const float was = add_s_p ? *add_s_p : 0.f;
#pragma unroll
  for (int i = 0; i < 4; ++i) {
    f32x4 c = __builtin_nontemporal_load(
        reinterpret_cast<const f32x4*>(p0 + 4 * i));
#pragma unroll
    for (int k = 1; k < KSPLIT; ++k)
      c += __builtin_nontemporal_load(reinterpret_cast<const f32x4*>(
          p0 + (size_t)k * 128 * KTOT + 4 * i));
    if (bt)
      *reinterpret_cast<uint2*>((unsigned short*)bt + (size_t)col64 * KTOT + rbase + 4 * i) =
          pack4(c);
    if (obase >= 0) {
#pragma unroll
      for (int j = 0; j < 4; ++j) {
        int row = rbase + 4 * i + j;
        float v = s * c[j];
        if (add_ptr && !hi) v = fmaf(was, add_ptr[(size_t)row * 64 + col64], v);
        if (accum) v += out[(size_t)row * 128 + obase + col64];
        out[(size_t)row * 128 + obase + col64] = v;
      }
    }
  }
}

// Combine partials + cross-half epilogue: out[:,64+c] = s_lo*lo[c] + s_hi*hi[c],
// bt_lo = raw lo (bf16 transposed). 256 blocks x 32 rows.
__global__ __launch_bounds__(256) void reduce_comb(
    const float* __restrict__ part, float* __restrict__ out,
    const float* s_lo_p, const float* s_hi_p, __hip_bfloat16* bt_lo) {
  const int t = threadIdx.x;
  const int c = t & 63;
  const int rbase = blockIdx.x * 32 + (t >> 6) * 8;
  const float* pl = part + (size_t)c * KTOT + rbase;
  const float* ph = part + (size_t)(c + 64) * KTOT + rbase;
  const float sl = *s_lo_p, sh = *s_hi_p;
#pragma unroll
  for (int i = 0; i < 2; ++i) {
    f32x4 lo = __builtin_nontemporal_load(reinterpret_cast<const f32x4*>(pl + 4 * i));
    f32x4 hv = __builtin_nontemporal_load(reinterpret_cast<const f32x4*>(ph + 4 * i));
#pragma unroll
    for (int k = 1; k < KSPLIT; ++k) {
      lo += __builtin_nontemporal_load(reinterpret_cast<const f32x4*>(
          pl + (size_t)k * 128 * KTOT + 4 * i));
      hv += __builtin_nontemporal_load(reinterpret_cast<const f32x4*>(
          ph + (size_t)k * 128 * KTOT + 4 * i));
    }
    *reinterpret_cast<uint2*>((unsigned short*)bt_lo + (size_t)c * KTOT + rbase + 4 * i) =
        pack4(lo);
#pragma unroll
    for (int j = 0; j < 4; ++j) {
      int row = rbase + 4 * i + j;
      out[(size_t)row * 128 + 64 + c] = sl * lo[j] + sh * hv[j];
    }
  }
}

extern "C" void kernel_launch(void* const* d_in, const int* in_sizes, int n_in,
                              void* d_out, int out_size, void* d_ws, size_t ws_size,
                              hipStream_t stream) {
  const float* A_p = (const float*)d_in[0];
  const float* A_n = (const float*)d_in[1];
  const float* x_p = (const float*)d_in[2];
  const float* x_n = (const float*)d_in[3];
  const float* w_p = (const float*)d_in[4];  // [3]
  const float* w_n = (const float*)d_in[5];  // [3]
  float* out = (float*)d_out;                // [8192][128]

  // ws layout (21 MiB):
  //   BTbig [192][8192] bf16: rows 0-63 x_p^T, 64-127 x_n^T, 128-191 Y1^T
  //   B3T   [128][8192] bf16: rows 0-63 P1^T, 64-127 T1^T
  //   part  [KSPLIT][128][8192] f32
  __hip_bfloat16* BTbig = (__hip_bfloat16*)d_ws;
  __hip_bfloat16* B3T = BTbig + (size_t)192 * KTOT;
  float* part = (float*)(B3T + (size_t)128 * KTOT);

  xpose_f32_bf16<<<128, 256, 0, stream>>>(x_p, BTbig);
  xpose_f32_bf16<<<128, 256, 0, stream>>>(x_n, BTbig + (size_t)64 * KTOT);

  // G1: [P1|Y1] = A_p @ [x_p|x_n]
  gemm_part<<<512, 512, 0, stream>>>(A_p, BTbig, part);
  // out[:,0:64] = wp0*x_p + wp1*P1; emit P1^T -> B3T[0:64], Y1^T -> BTbig[128:192]
  reduce_sep<<<256, 256, 0, stream>>>(part, out, w_p + 1, nullptr, x_p, w_p + 0,
                                      B3T, BTbig + (size_t)128 * KTOT, 0, -1, 0);

  // G2': [T1|T3] = A_n @ [x_n|Y1]
  gemm_part<<<512, 512, 0, stream>>>(A_n, BTbig + (size_t)64 * KTOT, part);
  // out[:,64:128] = wn0*T1 + wn2*T3; emit T1^T -> B3T[64:128]
  reduce_comb<<<256, 256, 0, stream>>>(part, out, w_n + 0, w_n + 2,
                                       B3T + (size_t)64 * KTOT);

  // G3: [P2|T2] = A_p @ [P1|T1]
  gemm_part<<<512, 512, 0, stream>>>(A_p, B3T, part);
  // out[:,0:64] += wp2*P2; out[:,64:128] += wn1*T2
  reduce_sep<<<256, 256, 0, stream>>>(part, out, w_p + 2, w_n + 1, nullptr, nullptr,
                                      nullptr, nullptr, 0, 64, 1);
}